// Round 16
// baseline (867.216 us; speedup 1.0000x reference)
//
#include <hip/hip_runtime.h>
#include <cfloat>
#include <cstddef>
#include <cstdint>

// ---------------------------------------------------------------------------
// SemanticRQVAE forward, round 16.
//   R15 + (1) dec2 as padded BN=256 S3=false GEMM (16 MFMA/barrier vs 8),
//   (2) A-LDS halved when S3=false (h-half only -> 73.7 KB, 2 blocks/CU),
//   (3) OUTH: dec1 / vq_quant skip never-read l-half writes (-134 MB HBM).
// Activation format, per row, per k-tile of 16 (64 B):
//   [u=0] h(k0..7) [u=1] h(k8..15) [u=2] l(k0..7) [u=3] l(k8..15)
// d_out layout (floats): recon | indices-as-float | recon_loss | commit_loss
// ---------------------------------------------------------------------------

#define BATCH   65536
#define EDIM    384
#define HDIM    512
#define NCODE   256
#define NQ      4

#define OUT_IDX_OFF 25165824
#define OUT_RL_OFF  25427968
#define WS_P0       0
#define WS_P1       33554432
#define WS_CBW      67108864
#define WS_CNORM    67633152
#define WS_COMMITP  67634176
#define WS_RECONP   67636224
#define WS_W1S      67637760
#define WS_W2S      67834368
#define WS_W3S      68096512
#define WS_W4S      68358656
#define WS_CBA      68555264
#define WS_G6       69079552
#define WS_ZN       69472768
#define WS_SSTAR    69538304
#define WS_IDXI     69800448

typedef _Float16 half8 __attribute__((ext_vector_type(8)));
typedef float    f32x16 __attribute__((ext_vector_type(16)));

__device__ __forceinline__ void cvt_hl8(const float* vs, half8& h, half8& l)
{
#pragma unroll
    for (int j = 0; j < 8; ++j) {
        _Float16 hv = (_Float16)vs[j];
        h[j] = hv;
        l[j] = (_Float16)(vs[j] - (float)hv);
    }
}

__device__ __forceinline__ void gll16(const unsigned short* g, unsigned short* l)
{
    __builtin_amdgcn_global_load_lds(
        (const __attribute__((address_space(1))) unsigned int*)g,
        (__attribute__((address_space(3))) unsigned int*)l, 16, 0, 0);
}

template <int N> __device__ __forceinline__ void waitvm()
{
    __builtin_amdgcn_sched_barrier(0);
    if constexpr (N == 0)      asm volatile("s_waitcnt vmcnt(0)" ::: "memory");
    else if constexpr (N == 2) asm volatile("s_waitcnt vmcnt(2)" ::: "memory");
    else if constexpr (N == 3) asm volatile("s_waitcnt vmcnt(3)" ::: "memory");
    else if constexpr (N == 4) asm volatile("s_waitcnt vmcnt(4)" ::: "memory");
    else if constexpr (N == 6) asm volatile("s_waitcnt vmcnt(6)" ::: "memory");
    __builtin_amdgcn_sched_barrier(0);
}
__device__ __forceinline__ void barrier_raw()
{
    __builtin_amdgcn_s_barrier();
    __builtin_amdgcn_sched_barrier(0);
}

// ---------------------------------------------------------------------------
// splits
// ---------------------------------------------------------------------------
__global__ __launch_bounds__(256)
void split_act(const float* __restrict__ src, unsigned short* __restrict__ dst,
               int K)
{
    int u = blockIdx.x * 256 + threadIdx.x;
    int upr = K >> 3;
    int row = u / upr;
    int rem = u % upr;
    int kt = rem >> 1, kh = rem & 1;
    const float* p = src + (size_t)row * K + kt * 16 + kh * 8;
    float vs[8];
#pragma unroll
    for (int j = 0; j < 8; ++j) vs[j] = p[j];
    half8 h, l;
    cvt_hl8(vs, h, l);
    unsigned short* o = dst + (size_t)row * (2 * K) + kt * 32 + kh * 8;
    *reinterpret_cast<half8*>(o)      = h;
    *reinterpret_cast<half8*>(o + 16) = l;
}

__device__ __forceinline__ void body_split_w(const float* __restrict__ W,
                                             unsigned short* __restrict__ out,
                                             int N, int u)
{
    int col  = u % N;
    int rem  = u / N;
    int kh   = rem & 1;
    int kt   = rem >> 1;
    int kbase = kt * 16 + kh * 8;
    float vs[8];
#pragma unroll
    for (int j = 0; j < 8; ++j) vs[j] = W[(size_t)(kbase + j) * N + col];
    half8 h, l;
    cvt_hl8(vs, h, l);
    *reinterpret_cast<half8*>(out + ((size_t)(kt * 4 + kh) * N + col) * 8)     = h;
    *reinterpret_cast<half8*>(out + ((size_t)(kt * 4 + 2 + kh) * N + col) * 8) = l;
}

__device__ __forceinline__ void body_split_cbw(const float* __restrict__ cb,
                                               unsigned short* __restrict__ out,
                                               int u)
{
    int col = u & 1023;
    int rem = u >> 10;
    int kh = rem & 1;
    int kt = rem >> 1;
    const float* p = cb + (size_t)col * HDIM + kt * 16 + kh * 8;
    float vs[8];
#pragma unroll
    for (int j = 0; j < 8; ++j) vs[j] = p[j];
    half8 h, l;
    cvt_hl8(vs, h, l);
    *reinterpret_cast<half8*>(out + ((size_t)(kt * 4 + kh) * 1024 + col) * 8)     = h;
    *reinterpret_cast<half8*>(out + ((size_t)(kt * 4 + 2 + kh) * 1024 + col) * 8) = l;
}

__device__ __forceinline__ void body_split_cba(const float* __restrict__ cb,
                                               unsigned short* __restrict__ out,
                                               int u)
{
    int row = u >> 6;
    int rem = u & 63;
    int kt = rem >> 1, kh = rem & 1;
    const float* p = cb + (size_t)row * HDIM + kt * 16 + kh * 8;
    float vs[8];
#pragma unroll
    for (int j = 0; j < 8; ++j) vs[j] = p[j];
    half8 h, l;
    cvt_hl8(vs, h, l);
    unsigned short* o = out + (size_t)row * 1024 + kt * 32 + kh * 8;
    *reinterpret_cast<half8*>(o)      = h;
    *reinterpret_cast<half8*>(o + 16) = l;
}

__global__ __launch_bounds__(256)
void split_wall(const float* __restrict__ ew1, const float* __restrict__ ew2,
                const float* __restrict__ dw1, const float* __restrict__ dw2,
                const float* __restrict__ cb,
                unsigned short* __restrict__ w1s, unsigned short* __restrict__ w2s,
                unsigned short* __restrict__ w3s, unsigned short* __restrict__ w4s,
                unsigned short* __restrict__ cbw, unsigned short* __restrict__ cba)
{
    const int b = blockIdx.x, tid = threadIdx.x;
    if (b < 96)        body_split_w(ew1, w1s, HDIM, b * 256 + tid);
    else if (b < 224)  body_split_w(ew2, w2s, HDIM, (b - 96) * 256 + tid);
    else if (b < 352)  body_split_w(dw1, w3s, HDIM, (b - 224) * 256 + tid);
    else if (b < 448)  body_split_w(dw2, w4s, EDIM, (b - 352) * 256 + tid);
    else if (b < 704)  body_split_cbw(cb, cbw, (b - 448) * 256 + tid);
    else               body_split_cba(cb, cba, (b - 704) * 256 + tid);
}

__global__ __launch_bounds__(64)
void cnorm_kernel(const float* __restrict__ cb, float* __restrict__ cnorm)
{
    const int code = blockIdx.x;
    const int lane = threadIdx.x;
    const float* r = cb + (size_t)code * HDIM;
    float s = 0.f;
    for (int k = lane; k < HDIM; k += 64) s = fmaf(r[k], r[k], s);
#pragma unroll
    for (int off = 32; off > 0; off >>= 1) s += __shfl_down(s, off);
    if (lane == 0) cnorm[code] = s;
}

__global__ __launch_bounds__(256)
void rownorm(const unsigned short* __restrict__ zs, float* __restrict__ zn)
{
    const int tid = threadIdx.x, wid = tid >> 6, lane = tid & 63;
    const int row = blockIdx.x * 4 + wid;
    const unsigned short* p = zs + (size_t)row * 1024
                                 + (lane >> 1) * 32 + (lane & 1) * 8;
    half8 h = *reinterpret_cast<const half8*>(p);
    half8 l = *reinterpret_cast<const half8*>(p + 16);
    float s = 0.f;
#pragma unroll
    for (int e = 0; e < 8; ++e) {
        float v = (float)h[e] + (float)l[e];
        s = fmaf(v, v, s);
    }
#pragma unroll
    for (int off = 32; off > 0; off >>= 1) s += __shfl_down(s, off);
    if (lane == 0) zn[row] = s;
}

// ---------------------------------------------------------------------------
// Pipelined MFMA GEMM, 8 waves / BM=256, 3-deep ring, counted vmcnt (R11).
// S3=true : full split-2 (3 MFMA/frag, A h+l staged, A-buf 8192 u16).
// S3=false: decoder precision (2 MFMA/frag = Ah*(Bh+Bl), A h only, buf 4096).
// OUTH=true: OMODE0 writes only the h-half (consumer is S3=false).
// OMODE 0: split-act out; 1: f32 + recon loss (col<N guard -> padded N ok);
// 2: raw f32 (ldc); 3: Gram mode (grid (6,1)).
// ---------------------------------------------------------------------------
template <int BN, int NKT, int OMODE, bool RELU, bool S3, bool OUTH>
__global__ __launch_bounds__(512, 2)
void gemm_pl(const unsigned short* __restrict__ Ain,
             const unsigned short* __restrict__ Wsp,
             const float* __restrict__ bias, void* __restrict__ Cout,
             const float* __restrict__ X, float* __restrict__ lossP,
             int N, int ldc)
{
    constexpr int WN  = BN / 64;
    constexpr int WM  = 8 / WN;
    constexpr int MR  = 256 / WM;
    constexpr int FM  = MR / 32;
    constexpr int K   = NKT * 16;
    constexpr int BOFF = S3 ? 8192 : 4096;      // A u16 per buffer (h+l / h)
    constexpr int BUFU = BOFF + 32 * BN;
    constexpr int GPI  = (S3 ? 2 : 1) + ((BN == 256) ? 2 : 1);

    __shared__ __align__(16) unsigned short lds[3][BUFU];

    const int tid  = threadIdx.x;
    const int wid  = tid >> 6;
    const int lane = tid & 63;
    const int l31  = lane & 31;
    const int lh   = lane >> 5;
    const int wm   = wid / WN;
    const int wn   = wid % WN;

    int row0, n0, bx = 0, by = 0, pair = 0;
    const unsigned short* Abase = Ain;
    if constexpr (OMODE == 3) {
        const int ptab[6] = {0, 0, 0, 1, 1, 2};
        const int qtab[6] = {1, 2, 3, 2, 3, 3};
        pair = blockIdx.x;
        Abase = Ain + (size_t)ptab[pair] * 256 * 1024;
        row0 = 0;
        n0   = qtab[pair] * 256;
    } else {
        int bidx = blockIdx.y * gridDim.x + blockIdx.x;
        const int nwg = gridDim.x * gridDim.y;
        if ((nwg & 7) == 0) {
            const int cpx = nwg >> 3;
            bidx = (bidx & 7) * cpx + (bidx >> 3);
        }
        bx = bidx % gridDim.x;
        by = bidx / gridDim.x;
        row0 = by * 256;
        n0   = bx * BN;
    }

    f32x16 acc[FM][2];
#pragma unroll
    for (int m = 0; m < FM; ++m)
#pragma unroll
        for (int n = 0; n < 2; ++n) acc[m][n] = (f32x16)(0.0f);

    auto stageA = [&](int buf, int kt) {
#pragma unroll
        for (int t = 0; t < (S3 ? 2 : 1); ++t) {
            const int i = t * 8 + wid;
            const int u = i >> 2;
            const int row = (i & 3) * 64 + lane;
            gll16(Abase + (size_t)(row0 + row) * (2 * K) + kt * 32 + u * 8,
                  &lds[buf][(size_t)i * 512 + (size_t)lane * 8]);
        }
    };
    auto stageB = [&](int buf, int kt) {
        const unsigned short* img = Wsp + (size_t)kt * 4 * N * 8;
        unsigned short* dstb = &lds[buf][BOFF];
        if constexpr (BN == 256) {
#pragma unroll
            for (int t = 0; t < 2; ++t) {
                const int i = t * 8 + wid;
                const int u = i >> 2;
                const int col = (i & 3) * 64 + lane;
                gll16(img + ((size_t)u * N + n0 + col) * 8,
                      dstb + (size_t)i * 512 + (size_t)lane * 8);
            }
        } else {
            const int u = wid >> 1;
            const int col = (wid & 1) * 64 + lane;
            gll16(img + ((size_t)u * N + n0 + col) * 8,
                  dstb + (size_t)wid * 512 + (size_t)lane * 8);
        }
    };
    auto compute = [&](int buf) {
        const unsigned short* Ab = &lds[buf][0];
        const unsigned short* Bb = &lds[buf][BOFF];
        half8 Ah[FM], Al[FM];
#pragma unroll
        for (int fm = 0; fm < FM; ++fm) {
            const int row = wm * MR + fm * 32 + l31;
            Ah[fm] = *reinterpret_cast<const half8*>(Ab + ((size_t)lh * 256 + row) * 8);
            if constexpr (S3)
                Al[fm] = *reinterpret_cast<const half8*>(Ab + ((size_t)(2 + lh) * 256 + row) * 8);
        }
#pragma unroll
        for (int nt = 0; nt < 2; ++nt) {
            const int col = wn * 64 + nt * 32 + l31;
            half8 Bh = *reinterpret_cast<const half8*>(Bb + ((size_t)lh * BN + col) * 8);
            half8 Bl = *reinterpret_cast<const half8*>(Bb + ((size_t)(2 + lh) * BN + col) * 8);
#pragma unroll
            for (int fm = 0; fm < FM; ++fm) {
                acc[fm][nt] = __builtin_amdgcn_mfma_f32_32x32x16_f16(Ah[fm], Bh, acc[fm][nt], 0, 0, 0);
                acc[fm][nt] = __builtin_amdgcn_mfma_f32_32x32x16_f16(Ah[fm], Bl, acc[fm][nt], 0, 0, 0);
                if constexpr (S3)
                    acc[fm][nt] = __builtin_amdgcn_mfma_f32_32x32x16_f16(Al[fm], Bh, acc[fm][nt], 0, 0, 0);
            }
        }
    };

    stageA(0, 0); stageB(0, 0);
    stageA(1, 1); stageB(1, 1);
    waitvm<GPI>();
    barrier_raw();
    for (int kt = 0; kt < NKT; ++kt) {
        const int cur = kt % 3;
        if (kt + 2 < NKT) { const int nb = (kt + 2) % 3; stageA(nb, kt + 2); stageB(nb, kt + 2); }
        compute(cur);
        if (kt < NKT - 2) waitvm<GPI>(); else waitvm<0>();
        barrier_raw();
    }

    if constexpr (OMODE == 0) {
        unsigned short* o = (unsigned short*)Cout;
        const size_t rs = (size_t)N * 2;
#pragma unroll
        for (int fm = 0; fm < FM; ++fm) {
#pragma unroll
            for (int nt = 0; nt < 2; ++nt) {
                const int col = n0 + wn * 64 + nt * 32 + l31;
                const float b = bias[col];
                const size_t cbo = (size_t)(col >> 4) * 32 + (size_t)((col >> 3) & 1) * 8 + (col & 7);
#pragma unroll
                for (int rg = 0; rg < 16; ++rg) {
                    const int row = row0 + wm * MR + fm * 32 + (rg & 3) + 8 * (rg >> 2) + 4 * lh;
                    float v = acc[fm][nt][rg] + b;
                    if (RELU) v = v > 0.f ? v : 0.f;
                    _Float16 hv = (_Float16)v;
                    union { _Float16 f; unsigned short u; } ch;
                    ch.f = hv;
                    o[(size_t)row * rs + cbo] = ch.u;
                    if constexpr (!OUTH) {
                        _Float16 lv = (_Float16)(v - (float)hv);
                        union { _Float16 f; unsigned short u; } cl;
                        cl.f = lv;
                        o[(size_t)row * rs + cbo + 16] = cl.u;
                    }
                }
            }
        }
    } else if constexpr (OMODE == 1) {
        float* C = (float*)Cout;
        float lacc = 0.f;
#pragma unroll
        for (int fm = 0; fm < FM; ++fm) {
#pragma unroll
            for (int nt = 0; nt < 2; ++nt) {
                const int col = n0 + wn * 64 + nt * 32 + l31;
                if (col < N) {
                    const float b = bias[col];
#pragma unroll
                    for (int rg = 0; rg < 16; ++rg) {
                        const int row = row0 + wm * MR + fm * 32 + (rg & 3) + 8 * (rg >> 2) + 4 * lh;
                        float v = acc[fm][nt][rg] + b;
                        if (RELU) v = v > 0.f ? v : 0.f;
                        C[(size_t)row * N + col] = v;
                        float d = v - X[(size_t)row * N + col];
                        lacc = fmaf(d, d, lacc);
                    }
                }
            }
        }
        __shared__ float red[512];
        red[tid] = lacc;
        __syncthreads();
        for (int s = 256; s > 0; s >>= 1) {
            if (tid < s) red[tid] += red[tid + s];
            __syncthreads();
        }
        if (tid == 0) lossP[by * gridDim.x + bx] = red[0];
    } else if constexpr (OMODE == 2) {
        float* C = (float*)Cout;
#pragma unroll
        for (int fm = 0; fm < FM; ++fm) {
#pragma unroll
            for (int nt = 0; nt < 2; ++nt) {
                const int col = n0 + wn * 64 + nt * 32 + l31;
#pragma unroll
                for (int rg = 0; rg < 16; ++rg) {
                    const int row = row0 + wm * MR + fm * 32 + (rg & 3) + 8 * (rg >> 2) + 4 * lh;
                    C[(size_t)row * ldc + col] = acc[fm][nt][rg];
                }
            }
        }
    } else {
        float* C = (float*)Cout + (size_t)pair * 65536;
#pragma unroll
        for (int fm = 0; fm < FM; ++fm) {
#pragma unroll
            for (int nt = 0; nt < 2; ++nt) {
                const int colL = wn * 64 + nt * 32 + l31;
#pragma unroll
                for (int rg = 0; rg < 16; ++rg) {
                    const int row = wm * MR + fm * 32 + (rg & 3) + 8 * (rg >> 2) + 4 * lh;
                    C[(size_t)row * 256 + colL] = acc[fm][nt][rg];
                }
            }
        }
    }
}

// ---------------------------------------------------------------------------
// Sequential Gram-corrected argmax over scores S [rows][1024] (R10-proven).
// ---------------------------------------------------------------------------
__global__ __launch_bounds__(256)
void vq_argmax(const float* __restrict__ S,
               const float* __restrict__ G6,
               const float* __restrict__ cnorm,
               float* __restrict__ idx_out,
               int* __restrict__ idxi,
               float* __restrict__ sstar,
               int rowbase)
{
    const int tid = threadIdx.x, wid = tid >> 6, lane = tid & 63;
    const int lrow = blockIdx.x * 4 + wid;
    const int grow = rowbase + lrow;
    const float* srow = S + (size_t)lrow * 1024;
    const int c0 = lane * 4;

    int iprev0 = 0, iprev1 = 0, iprev2 = 0;

#pragma unroll
    for (int q = 0; q < NQ; ++q) {
        float4 sv = *reinterpret_cast<const float4*>(srow + q * 256 + c0);
        float a[4] = {sv.x, sv.y, sv.z, sv.w};
        if (q >= 1) {
            const float* g = G6 + ((size_t)(q - 1) * 256 + iprev0) * 256 + c0;
            float4 gv = *reinterpret_cast<const float4*>(g);
            a[0] -= gv.x; a[1] -= gv.y; a[2] -= gv.z; a[3] -= gv.w;
        }
        if (q >= 2) {
            const float* g = G6 + ((size_t)(q + 1) * 256 + iprev1) * 256 + c0;
            float4 gv = *reinterpret_cast<const float4*>(g);
            a[0] -= gv.x; a[1] -= gv.y; a[2] -= gv.z; a[3] -= gv.w;
        }
        if (q >= 3) {
            const float* g = G6 + ((size_t)5 * 256 + iprev2) * 256 + c0;
            float4 gv = *reinterpret_cast<const float4*>(g);
            a[0] -= gv.x; a[1] -= gv.y; a[2] -= gv.z; a[3] -= gv.w;
        }
        float4 cnv = *reinterpret_cast<const float4*>(cnorm + q * 256 + c0);
        float cna[4] = {cnv.x, cnv.y, cnv.z, cnv.w};

        float bv = -FLT_MAX;
        int   bi = 0;
#pragma unroll
        for (int j = 0; j < 4; ++j) {
            float s = 2.f * a[j] - cna[j];
            const int code = c0 + j;
            if (s > bv || (s == bv && code < bi)) { bv = s; bi = code; }
        }
#pragma unroll
        for (int m = 1; m < 64; m <<= 1) {
            float ov = __shfl_xor(bv, m, 64);
            int   oi = __shfl_xor(bi, m, 64);
            if (ov > bv || (ov == bv && oi < bi)) { bv = ov; bi = oi; }
        }
        if (q == 0) iprev0 = bi;
        else if (q == 1) iprev1 = bi;
        else if (q == 2) iprev2 = bi;
        if (lane == 0) {
            idxi[q * 65536 + grow]  = bi;
            sstar[q * 65536 + grow] = bv;
            idx_out[(size_t)grow * NQ + q] = (float)bi;
        }
    }
}

// ---------------------------------------------------------------------------
// quant = sum of chosen codes (h-half only; dec1 is S3=false) + commit.
// ---------------------------------------------------------------------------
__global__ __launch_bounds__(256)
void vq_quant(const int* __restrict__ idxi, const float* __restrict__ sstar,
              const float* __restrict__ zn, const float* __restrict__ cb,
              unsigned short* __restrict__ qout, float* __restrict__ commitP)
{
    __shared__ float red[256];
    const int tid = threadIdx.x, wid = tid >> 6, lane = tid & 63;
    float ca = 0.f;

#pragma unroll
    for (int t = 0; t < 8; ++t) {
        const int row = blockIdx.x * 32 + wid * 8 + t;
        const int i0 = idxi[row],          i1 = idxi[65536 + row];
        const int i2 = idxi[131072 + row], i3 = idxi[196608 + row];
        const int koff = lane * 8;
        const float* c0 = cb + ((size_t)(0 * NCODE + i0)) * HDIM + koff;
        const float* c1 = cb + ((size_t)(1 * NCODE + i1)) * HDIM + koff;
        const float* c2 = cb + ((size_t)(2 * NCODE + i2)) * HDIM + koff;
        const float* c3 = cb + ((size_t)(3 * NCODE + i3)) * HDIM + koff;
        float q[8];
#pragma unroll
        for (int hh = 0; hh < 2; ++hh) {
            float4 v0 = *reinterpret_cast<const float4*>(c0 + hh * 4);
            float4 v1 = *reinterpret_cast<const float4*>(c1 + hh * 4);
            float4 v2 = *reinterpret_cast<const float4*>(c2 + hh * 4);
            float4 v3 = *reinterpret_cast<const float4*>(c3 + hh * 4);
            q[hh * 4 + 0] = ((v0.x + v1.x) + v2.x) + v3.x;
            q[hh * 4 + 1] = ((v0.y + v1.y) + v2.y) + v3.y;
            q[hh * 4 + 2] = ((v0.z + v1.z) + v2.z) + v3.z;
            q[hh * 4 + 3] = ((v0.w + v1.w) + v2.w) + v3.w;
        }
        half8 oh;
#pragma unroll
        for (int e = 0; e < 8; ++e) oh[e] = (_Float16)q[e];
        unsigned short* op = qout + (size_t)row * 1024
                                  + (lane >> 1) * 32 + (lane & 1) * 8;
        *reinterpret_cast<half8*>(op) = oh;

        if (lane == 0) {
            float rn = zn[row];
            rn -= sstar[row];           float cm = rn;
            rn -= sstar[65536 + row];   cm += rn;
            rn -= sstar[131072 + row];  cm += rn;
            rn -= sstar[196608 + row];  cm += rn;
            ca += cm;
        }
    }

    red[tid] = ca;
    __syncthreads();
    for (int s = 128; s > 0; s >>= 1) {
        if (tid < s) red[tid] += red[tid + s];
        __syncthreads();
    }
    if (tid == 0) commitP[blockIdx.x] = red[0];
}

// ---------------------------------------------------------------------------
__global__ __launch_bounds__(256)
void loss_reduce(const float* __restrict__ cP, int nc,
                 const float* __restrict__ rP, int nr,
                 float* __restrict__ out2)
{
    __shared__ float red[256];
    const int tid = threadIdx.x;

    float s = 0.f;
    for (int i = tid; i < nc; i += 256) s += cP[i];
    red[tid] = s;
    __syncthreads();
    for (int st = 128; st > 0; st >>= 1) {
        if (tid < st) red[tid] += red[tid + st];
        __syncthreads();
    }
    float ctot = red[0];
    __syncthreads();

    s = 0.f;
    for (int i = tid; i < nr; i += 256) s += rP[i];
    red[tid] = s;
    __syncthreads();
    for (int st = 128; st > 0; st >>= 1) {
        if (tid < st) red[tid] += red[tid + st];
        __syncthreads();
    }
    if (tid == 0) {
        out2[0] = red[0] / ((float)BATCH * (float)EDIM);
        out2[1] = 0.25f * ctot / ((float)BATCH * (float)HDIM);
    }
}

// ---------------------------------------------------------------------------
extern "C" void kernel_launch(void* const* d_in, const int* in_sizes, int n_in,
                              void* d_out, int out_size, void* d_ws, size_t ws_size,
                              hipStream_t stream)
{
    const float* x   = (const float*)d_in[0];
    const float* ew1 = (const float*)d_in[1];
    const float* eb1 = (const float*)d_in[2];
    const float* ew2 = (const float*)d_in[3];
    const float* eb2 = (const float*)d_in[4];
    const float* cb  = (const float*)d_in[5];
    const float* dw1 = (const float*)d_in[6];
    const float* db1 = (const float*)d_in[7];
    const float* dw2 = (const float*)d_in[8];
    const float* db2 = (const float*)d_in[9];

    float* out = (float*)d_out;
    float* ws  = (float*)d_ws;
    unsigned short* P0  = (unsigned short*)(ws + WS_P0);
    unsigned short* P1  = (unsigned short*)(ws + WS_P1);
    unsigned short* XS  = P1;
    float* Sbuf = ws + WS_P0;
    unsigned short* cbw = (unsigned short*)(ws + WS_CBW);
    unsigned short* cba = (unsigned short*)(ws + WS_CBA);
    float* G6 = ws + WS_G6;
    float* zn = ws + WS_ZN;
    float* ss = ws + WS_SSTAR;
    int*   ii = (int*)(ws + WS_IDXI);
    float* cn = ws + WS_CNORM;
    float* cP = ws + WS_COMMITP;
    float* rP = ws + WS_RECONP;
    unsigned short* w1s = (unsigned short*)(ws + WS_W1S);
    unsigned short* w2s = (unsigned short*)(ws + WS_W2S);
    unsigned short* w3s = (unsigned short*)(ws + WS_W3S);
    unsigned short* w4s = (unsigned short*)(ws + WS_W4S);

    // prep
    cnorm_kernel<<<NQ * NCODE, 64, 0, stream>>>(cb, cn);
    split_act<<<BATCH * 48 / 256, 256, 0, stream>>>(x, XS, EDIM);
    split_wall<<<960, 256, 0, stream>>>(ew1, ew2, dw1, dw2, cb,
                                        w1s, w2s, w3s, w4s, cbw, cba);

    // Gram: one dispatch, 6 blocks (full precision)
    gemm_pl<256, 32, 3, false, true, false><<<dim3(6, 1), 512, 0, stream>>>(
        cba, cbw, nullptr, G6, nullptr, nullptr, 1024, 256);

    // encoder (full precision): x-split (P1) -> h1-split (P0) -> z-split (P1)
    gemm_pl<256, 24, 0, true, true, false><<<dim3(HDIM / 256, BATCH / 256), 512, 0, stream>>>(
        XS, w1s, eb1, P0, nullptr, nullptr, HDIM, HDIM);
    gemm_pl<256, 32, 0, false, true, false><<<dim3(HDIM / 256, BATCH / 256), 512, 0, stream>>>(
        P0, w2s, eb2, P1, nullptr, nullptr, HDIM, HDIM);

    // |z|^2 per row
    rownorm<<<BATCH / 4, 256, 0, stream>>>(P1, zn);

    // fused score GEMM (N=1024, full precision) + streaming argmax
    float* idxo = out + OUT_IDX_OFF;
    for (int half = 0; half < 2; ++half) {
        const int rowbase = half * 32768;
        gemm_pl<256, 32, 2, false, true, false><<<dim3(4, 128), 512, 0, stream>>>(
            P1 + (size_t)rowbase * 1024, cbw, nullptr, Sbuf,
            nullptr, nullptr, 1024, 1024);
        vq_argmax<<<8192, 256, 0, stream>>>(Sbuf, G6, cn, idxo, ii, ss, rowbase);
    }

    // quant (h-only) -> P0, + commit partials
    vq_quant<<<BATCH / 32, 256, 0, stream>>>(ii, ss, zn, cb, P0, cP);

    // decoder (S3=false): dec1 h-only out; dec2 padded BN=256
    gemm_pl<256, 32, 0, true, false, true><<<dim3(HDIM / 256, BATCH / 256), 512, 0, stream>>>(
        P0, w3s, db1, P1, nullptr, nullptr, HDIM, HDIM);
    gemm_pl<256, 32, 1, false, false, false><<<dim3(2, BATCH / 256), 512, 0, stream>>>(
        P1, w4s, db2, out, x, rP, EDIM, EDIM);

    // losses
    loss_reduce<<<1, 256, 0, stream>>>(cP, BATCH / 32, rP,
                                       2 * (BATCH / 256),
                                       out + OUT_RL_OFF);
}

// Round 17
// 846.706 us; speedup vs baseline: 1.0242x; 1.0242x over previous
//
#include <hip/hip_runtime.h>
#include <cfloat>
#include <cstddef>
#include <cstdint>

// ---------------------------------------------------------------------------
// SemanticRQVAE forward, round 17.
//   R15 flow with dec2 back at BN=128 (padding disproven twice), keeping
//   R16's neutral-positive pieces: S3=false A-LDS halved (dec2 now 51 KB ->
//   3 blocks/CU), dec1 h-only outputs (OUTH), vq_quant h-only writes.
// Activation format, per row, per k-tile of 16 (64 B):
//   [u=0] h(k0..7) [u=1] h(k8..15) [u=2] l(k0..7) [u=3] l(k8..15)
// d_out layout (floats): recon | indices-as-float | recon_loss | commit_loss
// ---------------------------------------------------------------------------

#define BATCH   65536
#define EDIM    384
#define HDIM    512
#define NCODE   256
#define NQ      4

#define OUT_IDX_OFF 25165824
#define OUT_RL_OFF  25427968
#define WS_P0       0
#define WS_P1       33554432
#define WS_CBW      67108864
#define WS_CNORM    67633152
#define WS_COMMITP  67634176
#define WS_RECONP   67636224
#define WS_W1S      67637760
#define WS_W2S      67834368
#define WS_W3S      68096512
#define WS_W4S      68358656
#define WS_CBA      68555264
#define WS_G6       69079552
#define WS_ZN       69472768
#define WS_SSTAR    69538304
#define WS_IDXI     69800448

typedef _Float16 half8 __attribute__((ext_vector_type(8)));
typedef float    f32x16 __attribute__((ext_vector_type(16)));

__device__ __forceinline__ void cvt_hl8(const float* vs, half8& h, half8& l)
{
#pragma unroll
    for (int j = 0; j < 8; ++j) {
        _Float16 hv = (_Float16)vs[j];
        h[j] = hv;
        l[j] = (_Float16)(vs[j] - (float)hv);
    }
}

__device__ __forceinline__ void gll16(const unsigned short* g, unsigned short* l)
{
    __builtin_amdgcn_global_load_lds(
        (const __attribute__((address_space(1))) unsigned int*)g,
        (__attribute__((address_space(3))) unsigned int*)l, 16, 0, 0);
}

template <int N> __device__ __forceinline__ void waitvm()
{
    __builtin_amdgcn_sched_barrier(0);
    if constexpr (N == 0)      asm volatile("s_waitcnt vmcnt(0)" ::: "memory");
    else if constexpr (N == 2) asm volatile("s_waitcnt vmcnt(2)" ::: "memory");
    else if constexpr (N == 3) asm volatile("s_waitcnt vmcnt(3)" ::: "memory");
    else if constexpr (N == 4) asm volatile("s_waitcnt vmcnt(4)" ::: "memory");
    else if constexpr (N == 6) asm volatile("s_waitcnt vmcnt(6)" ::: "memory");
    __builtin_amdgcn_sched_barrier(0);
}
__device__ __forceinline__ void barrier_raw()
{
    __builtin_amdgcn_s_barrier();
    __builtin_amdgcn_sched_barrier(0);
}

// ---------------------------------------------------------------------------
// splits
// ---------------------------------------------------------------------------
__global__ __launch_bounds__(256)
void split_act(const float* __restrict__ src, unsigned short* __restrict__ dst,
               int K)
{
    int u = blockIdx.x * 256 + threadIdx.x;
    int upr = K >> 3;
    int row = u / upr;
    int rem = u % upr;
    int kt = rem >> 1, kh = rem & 1;
    const float* p = src + (size_t)row * K + kt * 16 + kh * 8;
    float vs[8];
#pragma unroll
    for (int j = 0; j < 8; ++j) vs[j] = p[j];
    half8 h, l;
    cvt_hl8(vs, h, l);
    unsigned short* o = dst + (size_t)row * (2 * K) + kt * 32 + kh * 8;
    *reinterpret_cast<half8*>(o)      = h;
    *reinterpret_cast<half8*>(o + 16) = l;
}

__device__ __forceinline__ void body_split_w(const float* __restrict__ W,
                                             unsigned short* __restrict__ out,
                                             int N, int u)
{
    int col  = u % N;
    int rem  = u / N;
    int kh   = rem & 1;
    int kt   = rem >> 1;
    int kbase = kt * 16 + kh * 8;
    float vs[8];
#pragma unroll
    for (int j = 0; j < 8; ++j) vs[j] = W[(size_t)(kbase + j) * N + col];
    half8 h, l;
    cvt_hl8(vs, h, l);
    *reinterpret_cast<half8*>(out + ((size_t)(kt * 4 + kh) * N + col) * 8)     = h;
    *reinterpret_cast<half8*>(out + ((size_t)(kt * 4 + 2 + kh) * N + col) * 8) = l;
}

__device__ __forceinline__ void body_split_cbw(const float* __restrict__ cb,
                                               unsigned short* __restrict__ out,
                                               int u)
{
    int col = u & 1023;
    int rem = u >> 10;
    int kh = rem & 1;
    int kt = rem >> 1;
    const float* p = cb + (size_t)col * HDIM + kt * 16 + kh * 8;
    float vs[8];
#pragma unroll
    for (int j = 0; j < 8; ++j) vs[j] = p[j];
    half8 h, l;
    cvt_hl8(vs, h, l);
    *reinterpret_cast<half8*>(out + ((size_t)(kt * 4 + kh) * 1024 + col) * 8)     = h;
    *reinterpret_cast<half8*>(out + ((size_t)(kt * 4 + 2 + kh) * 1024 + col) * 8) = l;
}

__device__ __forceinline__ void body_split_cba(const float* __restrict__ cb,
                                               unsigned short* __restrict__ out,
                                               int u)
{
    int row = u >> 6;
    int rem = u & 63;
    int kt = rem >> 1, kh = rem & 1;
    const float* p = cb + (size_t)row * HDIM + kt * 16 + kh * 8;
    float vs[8];
#pragma unroll
    for (int j = 0; j < 8; ++j) vs[j] = p[j];
    half8 h, l;
    cvt_hl8(vs, h, l);
    unsigned short* o = out + (size_t)row * 1024 + kt * 32 + kh * 8;
    *reinterpret_cast<half8*>(o)      = h;
    *reinterpret_cast<half8*>(o + 16) = l;
}

__global__ __launch_bounds__(256)
void split_wall(const float* __restrict__ ew1, const float* __restrict__ ew2,
                const float* __restrict__ dw1, const float* __restrict__ dw2,
                const float* __restrict__ cb,
                unsigned short* __restrict__ w1s, unsigned short* __restrict__ w2s,
                unsigned short* __restrict__ w3s, unsigned short* __restrict__ w4s,
                unsigned short* __restrict__ cbw, unsigned short* __restrict__ cba)
{
    const int b = blockIdx.x, tid = threadIdx.x;
    if (b < 96)        body_split_w(ew1, w1s, HDIM, b * 256 + tid);
    else if (b < 224)  body_split_w(ew2, w2s, HDIM, (b - 96) * 256 + tid);
    else if (b < 352)  body_split_w(dw1, w3s, HDIM, (b - 224) * 256 + tid);
    else if (b < 448)  body_split_w(dw2, w4s, EDIM, (b - 352) * 256 + tid);
    else if (b < 704)  body_split_cbw(cb, cbw, (b - 448) * 256 + tid);
    else               body_split_cba(cb, cba, (b - 704) * 256 + tid);
}

__global__ __launch_bounds__(64)
void cnorm_kernel(const float* __restrict__ cb, float* __restrict__ cnorm)
{
    const int code = blockIdx.x;
    const int lane = threadIdx.x;
    const float* r = cb + (size_t)code * HDIM;
    float s = 0.f;
    for (int k = lane; k < HDIM; k += 64) s = fmaf(r[k], r[k], s);
#pragma unroll
    for (int off = 32; off > 0; off >>= 1) s += __shfl_down(s, off);
    if (lane == 0) cnorm[code] = s;
}

__global__ __launch_bounds__(256)
void rownorm(const unsigned short* __restrict__ zs, float* __restrict__ zn)
{
    const int tid = threadIdx.x, wid = tid >> 6, lane = tid & 63;
    const int row = blockIdx.x * 4 + wid;
    const unsigned short* p = zs + (size_t)row * 1024
                                 + (lane >> 1) * 32 + (lane & 1) * 8;
    half8 h = *reinterpret_cast<const half8*>(p);
    half8 l = *reinterpret_cast<const half8*>(p + 16);
    float s = 0.f;
#pragma unroll
    for (int e = 0; e < 8; ++e) {
        float v = (float)h[e] + (float)l[e];
        s = fmaf(v, v, s);
    }
#pragma unroll
    for (int off = 32; off > 0; off >>= 1) s += __shfl_down(s, off);
    if (lane == 0) zn[row] = s;
}

// ---------------------------------------------------------------------------
// Pipelined MFMA GEMM, 8 waves / BM=256, 3-deep ring, counted vmcnt (R11).
// S3=true : full split-2 (3 MFMA/frag, A h+l staged, A-buf 8192 u16).
// S3=false: decoder precision (2 MFMA/frag = Ah*(Bh+Bl), A h only, buf 4096).
// OUTH=true: OMODE0 writes only the h-half (consumer is S3=false).
// OMODE 0: split-act out; 1: f32 + recon loss; 2: raw f32 (ldc); 3: Gram.
// ---------------------------------------------------------------------------
template <int BN, int NKT, int OMODE, bool RELU, bool S3, bool OUTH>
__global__ __launch_bounds__(512, 2)
void gemm_pl(const unsigned short* __restrict__ Ain,
             const unsigned short* __restrict__ Wsp,
             const float* __restrict__ bias, void* __restrict__ Cout,
             const float* __restrict__ X, float* __restrict__ lossP,
             int N, int ldc)
{
    constexpr int WN  = BN / 64;
    constexpr int WM  = 8 / WN;
    constexpr int MR  = 256 / WM;
    constexpr int FM  = MR / 32;
    constexpr int K   = NKT * 16;
    constexpr int BOFF = S3 ? 8192 : 4096;
    constexpr int BUFU = BOFF + 32 * BN;
    constexpr int GPI  = (S3 ? 2 : 1) + ((BN == 256) ? 2 : 1);

    __shared__ __align__(16) unsigned short lds[3][BUFU];

    const int tid  = threadIdx.x;
    const int wid  = tid >> 6;
    const int lane = tid & 63;
    const int l31  = lane & 31;
    const int lh   = lane >> 5;
    const int wm   = wid / WN;
    const int wn   = wid % WN;

    int row0, n0, bx = 0, by = 0, pair = 0;
    const unsigned short* Abase = Ain;
    if constexpr (OMODE == 3) {
        const int ptab[6] = {0, 0, 0, 1, 1, 2};
        const int qtab[6] = {1, 2, 3, 2, 3, 3};
        pair = blockIdx.x;
        Abase = Ain + (size_t)ptab[pair] * 256 * 1024;
        row0 = 0;
        n0   = qtab[pair] * 256;
    } else {
        int bidx = blockIdx.y * gridDim.x + blockIdx.x;
        const int nwg = gridDim.x * gridDim.y;
        if ((nwg & 7) == 0) {
            const int cpx = nwg >> 3;
            bidx = (bidx & 7) * cpx + (bidx >> 3);
        }
        bx = bidx % gridDim.x;
        by = bidx / gridDim.x;
        row0 = by * 256;
        n0   = bx * BN;
    }

    f32x16 acc[FM][2];
#pragma unroll
    for (int m = 0; m < FM; ++m)
#pragma unroll
        for (int n = 0; n < 2; ++n) acc[m][n] = (f32x16)(0.0f);

    auto stageA = [&](int buf, int kt) {
#pragma unroll
        for (int t = 0; t < (S3 ? 2 : 1); ++t) {
            const int i = t * 8 + wid;
            const int u = i >> 2;
            const int row = (i & 3) * 64 + lane;
            gll16(Abase + (size_t)(row0 + row) * (2 * K) + kt * 32 + u * 8,
                  &lds[buf][(size_t)i * 512 + (size_t)lane * 8]);
        }
    };
    auto stageB = [&](int buf, int kt) {
        const unsigned short* img = Wsp + (size_t)kt * 4 * N * 8;
        unsigned short* dstb = &lds[buf][BOFF];
        if constexpr (BN == 256) {
#pragma unroll
            for (int t = 0; t < 2; ++t) {
                const int i = t * 8 + wid;
                const int u = i >> 2;
                const int col = (i & 3) * 64 + lane;
                gll16(img + ((size_t)u * N + n0 + col) * 8,
                      dstb + (size_t)i * 512 + (size_t)lane * 8);
            }
        } else {
            const int u = wid >> 1;
            const int col = (wid & 1) * 64 + lane;
            gll16(img + ((size_t)u * N + n0 + col) * 8,
                  dstb + (size_t)wid * 512 + (size_t)lane * 8);
        }
    };
    auto compute = [&](int buf) {
        const unsigned short* Ab = &lds[buf][0];
        const unsigned short* Bb = &lds[buf][BOFF];
        half8 Ah[FM], Al[FM];
#pragma unroll
        for (int fm = 0; fm < FM; ++fm) {
            const int row = wm * MR + fm * 32 + l31;
            Ah[fm] = *reinterpret_cast<const half8*>(Ab + ((size_t)lh * 256 + row) * 8);
            if constexpr (S3)
                Al[fm] = *reinterpret_cast<const half8*>(Ab + ((size_t)(2 + lh) * 256 + row) * 8);
        }
#pragma unroll
        for (int nt = 0; nt < 2; ++nt) {
            const int col = wn * 64 + nt * 32 + l31;
            half8 Bh = *reinterpret_cast<const half8*>(Bb + ((size_t)lh * BN + col) * 8);
            half8 Bl = *reinterpret_cast<const half8*>(Bb + ((size_t)(2 + lh) * BN + col) * 8);
#pragma unroll
            for (int fm = 0; fm < FM; ++fm) {
                acc[fm][nt] = __builtin_amdgcn_mfma_f32_32x32x16_f16(Ah[fm], Bh, acc[fm][nt], 0, 0, 0);
                acc[fm][nt] = __builtin_amdgcn_mfma_f32_32x32x16_f16(Ah[fm], Bl, acc[fm][nt], 0, 0, 0);
                if constexpr (S3)
                    acc[fm][nt] = __builtin_amdgcn_mfma_f32_32x32x16_f16(Al[fm], Bh, acc[fm][nt], 0, 0, 0);
            }
        }
    };

    stageA(0, 0); stageB(0, 0);
    stageA(1, 1); stageB(1, 1);
    waitvm<GPI>();
    barrier_raw();
    for (int kt = 0; kt < NKT; ++kt) {
        const int cur = kt % 3;
        if (kt + 2 < NKT) { const int nb = (kt + 2) % 3; stageA(nb, kt + 2); stageB(nb, kt + 2); }
        compute(cur);
        if (kt < NKT - 2) waitvm<GPI>(); else waitvm<0>();
        barrier_raw();
    }

    if constexpr (OMODE == 0) {
        unsigned short* o = (unsigned short*)Cout;
        const size_t rs = (size_t)N * 2;
#pragma unroll
        for (int fm = 0; fm < FM; ++fm) {
#pragma unroll
            for (int nt = 0; nt < 2; ++nt) {
                const int col = n0 + wn * 64 + nt * 32 + l31;
                const float b = bias[col];
                const size_t cbo = (size_t)(col >> 4) * 32 + (size_t)((col >> 3) & 1) * 8 + (col & 7);
#pragma unroll
                for (int rg = 0; rg < 16; ++rg) {
                    const int row = row0 + wm * MR + fm * 32 + (rg & 3) + 8 * (rg >> 2) + 4 * lh;
                    float v = acc[fm][nt][rg] + b;
                    if (RELU) v = v > 0.f ? v : 0.f;
                    _Float16 hv = (_Float16)v;
                    union { _Float16 f; unsigned short u; } ch;
                    ch.f = hv;
                    o[(size_t)row * rs + cbo] = ch.u;
                    if constexpr (!OUTH) {
                        _Float16 lv = (_Float16)(v - (float)hv);
                        union { _Float16 f; unsigned short u; } cl;
                        cl.f = lv;
                        o[(size_t)row * rs + cbo + 16] = cl.u;
                    }
                }
            }
        }
    } else if constexpr (OMODE == 1) {
        float* C = (float*)Cout;
        float lacc = 0.f;
#pragma unroll
        for (int fm = 0; fm < FM; ++fm) {
#pragma unroll
            for (int nt = 0; nt < 2; ++nt) {
                const int col = n0 + wn * 64 + nt * 32 + l31;
                if (col < N) {
                    const float b = bias[col];
#pragma unroll
                    for (int rg = 0; rg < 16; ++rg) {
                        const int row = row0 + wm * MR + fm * 32 + (rg & 3) + 8 * (rg >> 2) + 4 * lh;
                        float v = acc[fm][nt][rg] + b;
                        if (RELU) v = v > 0.f ? v : 0.f;
                        C[(size_t)row * N + col] = v;
                        float d = v - X[(size_t)row * N + col];
                        lacc = fmaf(d, d, lacc);
                    }
                }
            }
        }
        __shared__ float red[512];
        red[tid] = lacc;
        __syncthreads();
        for (int s = 256; s > 0; s >>= 1) {
            if (tid < s) red[tid] += red[tid + s];
            __syncthreads();
        }
        if (tid == 0) lossP[by * gridDim.x + bx] = red[0];
    } else if constexpr (OMODE == 2) {
        float* C = (float*)Cout;
#pragma unroll
        for (int fm = 0; fm < FM; ++fm) {
#pragma unroll
            for (int nt = 0; nt < 2; ++nt) {
                const int col = n0 + wn * 64 + nt * 32 + l31;
#pragma unroll
                for (int rg = 0; rg < 16; ++rg) {
                    const int row = row0 + wm * MR + fm * 32 + (rg & 3) + 8 * (rg >> 2) + 4 * lh;
                    C[(size_t)row * ldc + col] = acc[fm][nt][rg];
                }
            }
        }
    } else {
        float* C = (float*)Cout + (size_t)pair * 65536;
#pragma unroll
        for (int fm = 0; fm < FM; ++fm) {
#pragma unroll
            for (int nt = 0; nt < 2; ++nt) {
                const int colL = wn * 64 + nt * 32 + l31;
#pragma unroll
                for (int rg = 0; rg < 16; ++rg) {
                    const int row = wm * MR + fm * 32 + (rg & 3) + 8 * (rg >> 2) + 4 * lh;
                    C[(size_t)row * 256 + colL] = acc[fm][nt][rg];
                }
            }
        }
    }
}

// ---------------------------------------------------------------------------
// Sequential Gram-corrected argmax over scores S [rows][1024] (R10-proven).
// ---------------------------------------------------------------------------
__global__ __launch_bounds__(256)
void vq_argmax(const float* __restrict__ S,
               const float* __restrict__ G6,
               const float* __restrict__ cnorm,
               float* __restrict__ idx_out,
               int* __restrict__ idxi,
               float* __restrict__ sstar,
               int rowbase)
{
    const int tid = threadIdx.x, wid = tid >> 6, lane = tid & 63;
    const int lrow = blockIdx.x * 4 + wid;
    const int grow = rowbase + lrow;
    const float* srow = S + (size_t)lrow * 1024;
    const int c0 = lane * 4;

    int iprev0 = 0, iprev1 = 0, iprev2 = 0;

#pragma unroll
    for (int q = 0; q < NQ; ++q) {
        float4 sv = *reinterpret_cast<const float4*>(srow + q * 256 + c0);
        float a[4] = {sv.x, sv.y, sv.z, sv.w};
        if (q >= 1) {
            const float* g = G6 + ((size_t)(q - 1) * 256 + iprev0) * 256 + c0;
            float4 gv = *reinterpret_cast<const float4*>(g);
            a[0] -= gv.x; a[1] -= gv.y; a[2] -= gv.z; a[3] -= gv.w;
        }
        if (q >= 2) {
            const float* g = G6 + ((size_t)(q + 1) * 256 + iprev1) * 256 + c0;
            float4 gv = *reinterpret_cast<const float4*>(g);
            a[0] -= gv.x; a[1] -= gv.y; a[2] -= gv.z; a[3] -= gv.w;
        }
        if (q >= 3) {
            const float* g = G6 + ((size_t)5 * 256 + iprev2) * 256 + c0;
            float4 gv = *reinterpret_cast<const float4*>(g);
            a[0] -= gv.x; a[1] -= gv.y; a[2] -= gv.z; a[3] -= gv.w;
        }
        float4 cnv = *reinterpret_cast<const float4*>(cnorm + q * 256 + c0);
        float cna[4] = {cnv.x, cnv.y, cnv.z, cnv.w};

        float bv = -FLT_MAX;
        int   bi = 0;
#pragma unroll
        for (int j = 0; j < 4; ++j) {
            float s = 2.f * a[j] - cna[j];
            const int code = c0 + j;
            if (s > bv || (s == bv && code < bi)) { bv = s; bi = code; }
        }
#pragma unroll
        for (int m = 1; m < 64; m <<= 1) {
            float ov = __shfl_xor(bv, m, 64);
            int   oi = __shfl_xor(bi, m, 64);
            if (ov > bv || (ov == bv && oi < bi)) { bv = ov; bi = oi; }
        }
        if (q == 0) iprev0 = bi;
        else if (q == 1) iprev1 = bi;
        else if (q == 2) iprev2 = bi;
        if (lane == 0) {
            idxi[q * 65536 + grow]  = bi;
            sstar[q * 65536 + grow] = bv;
            idx_out[(size_t)grow * NQ + q] = (float)bi;
        }
    }
}

// ---------------------------------------------------------------------------
// quant = sum of chosen codes (h-half only; dec1 is S3=false) + commit.
// ---------------------------------------------------------------------------
__global__ __launch_bounds__(256)
void vq_quant(const int* __restrict__ idxi, const float* __restrict__ sstar,
              const float* __restrict__ zn, const float* __restrict__ cb,
              unsigned short* __restrict__ qout, float* __restrict__ commitP)
{
    __shared__ float red[256];
    const int tid = threadIdx.x, wid = tid >> 6, lane = tid & 63;
    float ca = 0.f;

#pragma unroll
    for (int t = 0; t < 8; ++t) {
        const int row = blockIdx.x * 32 + wid * 8 + t;
        const int i0 = idxi[row],          i1 = idxi[65536 + row];
        const int i2 = idxi[131072 + row], i3 = idxi[196608 + row];
        const int koff = lane * 8;
        const float* c0 = cb + ((size_t)(0 * NCODE + i0)) * HDIM + koff;
        const float* c1 = cb + ((size_t)(1 * NCODE + i1)) * HDIM + koff;
        const float* c2 = cb + ((size_t)(2 * NCODE + i2)) * HDIM + koff;
        const float* c3 = cb + ((size_t)(3 * NCODE + i3)) * HDIM + koff;
        float q[8];
#pragma unroll
        for (int hh = 0; hh < 2; ++hh) {
            float4 v0 = *reinterpret_cast<const float4*>(c0 + hh * 4);
            float4 v1 = *reinterpret_cast<const float4*>(c1 + hh * 4);
            float4 v2 = *reinterpret_cast<const float4*>(c2 + hh * 4);
            float4 v3 = *reinterpret_cast<const float4*>(c3 + hh * 4);
            q[hh * 4 + 0] = ((v0.x + v1.x) + v2.x) + v3.x;
            q[hh * 4 + 1] = ((v0.y + v1.y) + v2.y) + v3.y;
            q[hh * 4 + 2] = ((v0.z + v1.z) + v2.z) + v3.z;
            q[hh * 4 + 3] = ((v0.w + v1.w) + v2.w) + v3.w;
        }
        half8 oh;
#pragma unroll
        for (int e = 0; e < 8; ++e) oh[e] = (_Float16)q[e];
        unsigned short* op = qout + (size_t)row * 1024
                                  + (lane >> 1) * 32 + (lane & 1) * 8;
        *reinterpret_cast<half8*>(op) = oh;

        if (lane == 0) {
            float rn = zn[row];
            rn -= sstar[row];           float cm = rn;
            rn -= sstar[65536 + row];   cm += rn;
            rn -= sstar[131072 + row];  cm += rn;
            rn -= sstar[196608 + row];  cm += rn;
            ca += cm;
        }
    }

    red[tid] = ca;
    __syncthreads();
    for (int s = 128; s > 0; s >>= 1) {
        if (tid < s) red[tid] += red[tid + s];
        __syncthreads();
    }
    if (tid == 0) commitP[blockIdx.x] = red[0];
}

// ---------------------------------------------------------------------------
__global__ __launch_bounds__(256)
void loss_reduce(const float* __restrict__ cP, int nc,
                 const float* __restrict__ rP, int nr,
                 float* __restrict__ out2)
{
    __shared__ float red[256];
    const int tid = threadIdx.x;

    float s = 0.f;
    for (int i = tid; i < nc; i += 256) s += cP[i];
    red[tid] = s;
    __syncthreads();
    for (int st = 128; st > 0; st >>= 1) {
        if (tid < st) red[tid] += red[tid + st];
        __syncthreads();
    }
    float ctot = red[0];
    __syncthreads();

    s = 0.f;
    for (int i = tid; i < nr; i += 256) s += rP[i];
    red[tid] = s;
    __syncthreads();
    for (int st = 128; st > 0; st >>= 1) {
        if (tid < st) red[tid] += red[tid + st];
        __syncthreads();
    }
    if (tid == 0) {
        out2[0] = red[0] / ((float)BATCH * (float)EDIM);
        out2[1] = 0.25f * ctot / ((float)BATCH * (float)HDIM);
    }
}

// ---------------------------------------------------------------------------
extern "C" void kernel_launch(void* const* d_in, const int* in_sizes, int n_in,
                              void* d_out, int out_size, void* d_ws, size_t ws_size,
                              hipStream_t stream)
{
    const float* x   = (const float*)d_in[0];
    const float* ew1 = (const float*)d_in[1];
    const float* eb1 = (const float*)d_in[2];
    const float* ew2 = (const float*)d_in[3];
    const float* eb2 = (const float*)d_in[4];
    const float* cb  = (const float*)d_in[5];
    const float* dw1 = (const float*)d_in[6];
    const float* db1 = (const float*)d_in[7];
    const float* dw2 = (const float*)d_in[8];
    const float* db2 = (const float*)d_in[9];

    float* out = (float*)d_out;
    float* ws  = (float*)d_ws;
    unsigned short* P0  = (unsigned short*)(ws + WS_P0);
    unsigned short* P1  = (unsigned short*)(ws + WS_P1);
    unsigned short* XS  = P1;
    float* Sbuf = ws + WS_P0;
    unsigned short* cbw = (unsigned short*)(ws + WS_CBW);
    unsigned short* cba = (unsigned short*)(ws + WS_CBA);
    float* G6 = ws + WS_G6;
    float* zn = ws + WS_ZN;
    float* ss = ws + WS_SSTAR;
    int*   ii = (int*)(ws + WS_IDXI);
    float* cn = ws + WS_CNORM;
    float* cP = ws + WS_COMMITP;
    float* rP = ws + WS_RECONP;
    unsigned short* w1s = (unsigned short*)(ws + WS_W1S);
    unsigned short* w2s = (unsigned short*)(ws + WS_W2S);
    unsigned short* w3s = (unsigned short*)(ws + WS_W3S);
    unsigned short* w4s = (unsigned short*)(ws + WS_W4S);

    // prep
    cnorm_kernel<<<NQ * NCODE, 64, 0, stream>>>(cb, cn);
    split_act<<<BATCH * 48 / 256, 256, 0, stream>>>(x, XS, EDIM);
    split_wall<<<960, 256, 0, stream>>>(ew1, ew2, dw1, dw2, cb,
                                        w1s, w2s, w3s, w4s, cbw, cba);

    // Gram: one dispatch, 6 blocks (full precision)
    gemm_pl<256, 32, 3, false, true, false><<<dim3(6, 1), 512, 0, stream>>>(
        cba, cbw, nullptr, G6, nullptr, nullptr, 1024, 256);

    // encoder (full precision): x-split (P1) -> h1-split (P0) -> z-split (P1)
    gemm_pl<256, 24, 0, true, true, false><<<dim3(HDIM / 256, BATCH / 256), 512, 0, stream>>>(
        XS, w1s, eb1, P0, nullptr, nullptr, HDIM, HDIM);
    gemm_pl<256, 32, 0, false, true, false><<<dim3(HDIM / 256, BATCH / 256), 512, 0, stream>>>(
        P0, w2s, eb2, P1, nullptr, nullptr, HDIM, HDIM);

    // |z|^2 per row
    rownorm<<<BATCH / 4, 256, 0, stream>>>(P1, zn);

    // fused score GEMM (N=1024, full precision) + streaming argmax
    float* idxo = out + OUT_IDX_OFF;
    for (int half = 0; half < 2; ++half) {
        const int rowbase = half * 32768;
        gemm_pl<256, 32, 2, false, true, false><<<dim3(4, 128), 512, 0, stream>>>(
            P1 + (size_t)rowbase * 1024, cbw, nullptr, Sbuf,
            nullptr, nullptr, 1024, 1024);
        vq_argmax<<<8192, 256, 0, stream>>>(Sbuf, G6, cn, idxo, ii, ss, rowbase);
    }

    // quant (h-only) -> P0, + commit partials
    vq_quant<<<BATCH / 32, 256, 0, stream>>>(ii, ss, zn, cb, P0, cP);

    // decoder (S3=false): dec1 h-only out; dec2 BN=128 (R15 config, small LDS)
    gemm_pl<256, 32, 0, true, false, true><<<dim3(HDIM / 256, BATCH / 256), 512, 0, stream>>>(
        P0, w3s, db1, P1, nullptr, nullptr, HDIM, HDIM);
    gemm_pl<128, 32, 1, false, false, false><<<dim3(EDIM / 128, BATCH / 256), 512, 0, stream>>>(
        P1, w4s, db2, out, x, rP, EDIM, EDIM);

    // losses
    loss_reduce<<<1, 256, 0, stream>>>(cP, BATCH / 32, rP,
                                       (EDIM / 128) * (BATCH / 256),
                                       out + OUT_RL_OFF);
}